// Round 3
// baseline (4398.133 us; speedup 1.0000x reference)
//
#include <hip/hip_runtime.h>
#include <hip/hip_bf16.h>
#include <cstdint>
#include <cstddef>

typedef __attribute__((ext_vector_type(8))) short short8;
typedef __attribute__((ext_vector_type(4))) float f32x4;
typedef __attribute__((ext_vector_type(4))) unsigned short ushort4v;

#define B_ 64
#define S_ 128
#define T_ 32
#define H_ 1024
#define E_ 512
#define V_ 32000

__device__ __forceinline__ float bf2f(unsigned short s) {
  union { unsigned u; float f; } cv;
  cv.u = ((unsigned)s) << 16;
  return cv.f;
}
__device__ __forceinline__ unsigned short f2bf_bits(float f) {
  __hip_bfloat16 h = __float2bfloat16(f);
  return __builtin_bit_cast(unsigned short, h);
}

// ---------------- conversion / setup kernels ----------------

__global__ __launch_bounds__(256) void cvt_kernel(const float* __restrict__ in,
                                                  unsigned short* __restrict__ out, int n4) {
  int i = blockIdx.x * 256 + threadIdx.x;
  if (i >= n4) return;
  float4 v = ((const float4*)in)[i];
  ushort4v o;
  o.x = f2bf_bits(v.x); o.y = f2bf_bits(v.y); o.z = f2bf_bits(v.z); o.w = f2bf_bits(v.w);
  ((ushort4v*)out)[i] = o;
}

__global__ __launch_bounds__(256) void tok_gather_kernel(const float* __restrict__ emb,
                                                         const int* __restrict__ target,
                                                         unsigned short* __restrict__ tok) {
  int i = blockIdx.x * 256 + threadIdx.x;   // over (T-1)*B*E
  int e = i & (E_ - 1);
  int rest = i >> 9;        // / E_
  int b = rest & (B_ - 1);
  int t = rest >> 6;        // / B_
  int tg = target[b * T_ + t];
  tok[i] = f2bf_bits(emb[(size_t)tg * E_ + e]);
}

__global__ __launch_bounds__(256) void init_state_kernel(const float* __restrict__ enc,
                                                         float* __restrict__ state,
                                                         unsigned short* __restrict__ state_bf) {
  int i = blockIdx.x * 256 + threadIdx.x;   // B*H
  int b = i >> 10;
  int h = i & (H_ - 1);
  float v = enc[((size_t)b * S_ + (S_ - 1)) * H_ + h];
  state[i] = v;
  state_bf[i] = f2bf_bits(v);
}

__global__ __launch_bounds__(256) void sos_kernel(float* __restrict__ out) {
  int i = blockIdx.x * 256 + threadIdx.x;   // B*V
  int b = i / V_;
  int v = i - b * V_;
  out[(size_t)b * T_ * V_ + v] = (v == 1) ? 1.0f : 0.0f;
}

// ---------------- bf16 MFMA GEMM:  C[M,N] = A[M,K] * B[N,K]^T + bias ----------------
// 256 threads (4 waves), tile BM=64 x BN=64; wave w owns 16 columns.
// A,B row-major bf16 (bits in unsigned short). C fp32 or bf16.
// A/B fragments: m/n = lane&15, k-slot = (lane>>4)*8 + j  (same map for A and B,
// so any HW k-permutation cancels). C/D: col = lane&15, row = (lane>>4)*4 + reg
// [measured: learn_hip m89/m91].

template<bool OUT_BF16>
__device__ __forceinline__ void gemm_bt_device(
    const unsigned short* __restrict__ A, int lda,
    const unsigned short* __restrict__ Bm, int ldb,
    const float* __restrict__ bias,
    void* __restrict__ C, long long ldc,
    int K, int bn, int bm)
{
  const int wave = threadIdx.x >> 6;
  const int lane = threadIdx.x & 63;
  const int n0 = bn + wave * 16 + (lane & 15);
  const int ar = lane & 15;
  const int kg = (lane >> 4) * 8;

  const unsigned short* Bp = Bm + (size_t)n0 * ldb + kg;
  const unsigned short* Ap = A + (size_t)(bm + ar) * lda + kg;

  f32x4 acc0 = {0.f,0.f,0.f,0.f};
  f32x4 acc1 = {0.f,0.f,0.f,0.f};
  f32x4 acc2 = {0.f,0.f,0.f,0.f};
  f32x4 acc3 = {0.f,0.f,0.f,0.f};

  #pragma unroll 2
  for (int kk = 0; kk < K; kk += 32) {
    short8 bfrag = *(const short8*)(Bp + kk);
    short8 a0 = *(const short8*)(Ap + kk);
    short8 a1 = *(const short8*)(Ap + (size_t)16 * lda + kk);
    short8 a2 = *(const short8*)(Ap + (size_t)32 * lda + kk);
    short8 a3 = *(const short8*)(Ap + (size_t)48 * lda + kk);
    acc0 = __builtin_amdgcn_mfma_f32_16x16x32_bf16(a0, bfrag, acc0, 0, 0, 0);
    acc1 = __builtin_amdgcn_mfma_f32_16x16x32_bf16(a1, bfrag, acc1, 0, 0, 0);
    acc2 = __builtin_amdgcn_mfma_f32_16x16x32_bf16(a2, bfrag, acc2, 0, 0, 0);
    acc3 = __builtin_amdgcn_mfma_f32_16x16x32_bf16(a3, bfrag, acc3, 0, 0, 0);
  }

  const float bv = bias[n0];
  const int rbase = bm + (lane >> 4) * 4;
  f32x4 accs[4] = {acc0, acc1, acc2, acc3};
  #pragma unroll
  for (int mt = 0; mt < 4; ++mt) {
    #pragma unroll
    for (int r = 0; r < 4; ++r) {
      float v = accs[mt][r] + bv;
      size_t idx = (size_t)(rbase + mt * 16 + r) * (size_t)ldc + n0;
      if (OUT_BF16) ((unsigned short*)C)[idx] = f2bf_bits(v);
      else          ((float*)C)[idx] = v;
    }
  }
}

template<bool OUT_BF16>
__global__ __launch_bounds__(256) void gemm_bt_kernel(
    const unsigned short* __restrict__ A, int lda,
    const unsigned short* __restrict__ Bm, int ldb,
    const float* __restrict__ bias,
    void* __restrict__ C, long long ldc,
    int K)
{
  gemm_bt_device<OUT_BF16>(A, lda, Bm, ldb, bias, C, ldc, K,
                           blockIdx.x * 64, blockIdx.y * 64);
}

// Merged q + gh GEMM: both read state_b with K=H.
// blocks [0, 16):  q  = state @ Wq^T  + bq  -> qbuf  (N=1024, ldc=1024)
// blocks [16, 64): gh = state @ W_hh^T+ bhh -> ghbuf (N=3072, ldc=3072)
__global__ __launch_bounds__(256) void qgh_gemm_kernel(
    const unsigned short* __restrict__ state_b,
    const unsigned short* __restrict__ Wq_b, const float* __restrict__ bq,
    float* __restrict__ qbuf,
    const unsigned short* __restrict__ Whh_b, const float* __restrict__ bhh,
    float* __restrict__ ghbuf)
{
  if (blockIdx.x < H_ / 64) {
    gemm_bt_device<false>(state_b, H_, Wq_b, H_, bq, qbuf, H_, H_,
                          blockIdx.x * 64, 0);
  } else {
    gemm_bt_device<false>(state_b, H_, Whh_b, H_, bhh, ghbuf, 3 * H_, H_,
                          (blockIdx.x - H_ / 64) * 64, 0);
  }
}

// ---------------- fused attention (one block per batch element) ----------------
// scores[s] = sum_h Wa[h]*tanh(q[b,h]+keys[b,s,h]); w = softmax(scores);
// context[h] = sum_s w[s]*enc[b,s,h]; x = [token, context] (bf16)

__global__ __launch_bounds__(512) void attn_kernel(
    const float* __restrict__ q,
    const unsigned short* __restrict__ keys,
    const unsigned short* __restrict__ enc,
    const float* __restrict__ Wa,
    const unsigned short* __restrict__ tok_t,
    unsigned short* __restrict__ x)
{
  const int b = blockIdx.x;
  const int tid = threadIdx.x;
  __shared__ float s_q[H_];
  __shared__ float s_wa[H_];
  __shared__ float s_part[512];
  __shared__ float s_w[S_];
  __shared__ float s_bcast;

  for (int i = tid; i < H_; i += 512) { s_q[i] = q[b * H_ + i]; s_wa[i] = Wa[i]; }
  __syncthreads();

  // ---- scores: thread handles (s = tid&127, quarter = tid>>7 of H) ----
  {
    const int s = tid & (S_ - 1);
    const int h0 = (tid >> 7) * 256;
    const short8* kp = (const short8*)(keys + ((size_t)b * S_ + s) * H_ + h0);
    float acc = 0.f;
    #pragma unroll 4
    for (int hv = 0; hv < 32; ++hv) {   // 32*8 = 256 elems
      short8 kv = kp[hv];
      #pragma unroll
      for (int j = 0; j < 8; ++j) {
        int h = h0 + hv * 8 + j;
        float v = s_q[h] + bf2f((unsigned short)kv[j]);
        v = fminf(fmaxf(v, -15.f), 15.f);
        float e = __expf(2.f * v);
        float th = (e - 1.f) / (e + 1.f);
        acc += s_wa[h] * th;
      }
    }
    s_part[tid] = acc;
  }
  __syncthreads();
  if (tid < S_) {
    s_w[tid] = s_part[tid] + s_part[tid + 128] + s_part[tid + 256] + s_part[tid + 384];
  }
  __syncthreads();
  if (tid < 64) {
    float m = fmaxf(s_w[tid], s_w[tid + 64]);
    #pragma unroll
    for (int off = 32; off > 0; off >>= 1) m = fmaxf(m, __shfl_xor(m, off));
    if (tid == 0) s_bcast = m;
  }
  __syncthreads();
  const float mx = s_bcast;
  if (tid < S_) s_w[tid] = __expf(s_w[tid] - mx);
  __syncthreads();
  if (tid < 64) {
    float sm = s_w[tid] + s_w[tid + 64];
    #pragma unroll
    for (int off = 32; off > 0; off >>= 1) sm += __shfl_xor(sm, off);
    if (tid == 0) s_bcast = sm;
  }
  __syncthreads();
  const float inv = 1.0f / s_bcast;

  // ---- context: h = tid and tid+512 ----
  {
    float c0 = 0.f, c1 = 0.f;
    const unsigned short* ep = enc + (size_t)b * S_ * H_;
    #pragma unroll 4
    for (int s = 0; s < S_; ++s) {
      float w = s_w[s];
      c0 += w * bf2f(ep[s * H_ + tid]);
      c1 += w * bf2f(ep[s * H_ + tid + 512]);
    }
    c0 *= inv; c1 *= inv;
    x[b * (E_ + H_) + E_ + tid]       = f2bf_bits(c0);
    x[b * (E_ + H_) + E_ + tid + 512] = f2bf_bits(c1);
  }
  // ---- token copy into x[:, 0:E] ----
  x[b * (E_ + H_) + tid] = tok_t[b * E_ + tid];
}

// ---------------- GRU gate fuse ----------------

__global__ __launch_bounds__(256) void gate_kernel(
    const float* __restrict__ gi, const float* __restrict__ gh,
    float* __restrict__ state, unsigned short* __restrict__ state_bf)
{
  int i = blockIdx.x * 256 + threadIdx.x;  // B*H
  int b = i >> 10;
  int h = i & (H_ - 1);
  const float* gib = gi + (size_t)b * 3 * H_;
  const float* ghb = gh + (size_t)b * 3 * H_;
  float ir = gib[h], iz = gib[H_ + h], inn = gib[2 * H_ + h];
  float hr = ghb[h], hz = ghb[H_ + h], hn = ghb[2 * H_ + h];
  float r = 1.f / (1.f + __expf(-(ir + hr)));
  float z = 1.f / (1.f + __expf(-(iz + hz)));
  float t = inn + r * hn;
  t = fminf(fmaxf(t, -15.f), 15.f);
  float e = __expf(2.f * t);
  float nn = (e - 1.f) / (e + 1.f);
  float ns = (1.f - z) * nn + z * state[i];
  state[i] = ns;
  state_bf[i] = f2bf_bits(ns);
}

// ---------------- launcher ----------------

extern "C" void kernel_launch(void* const* d_in, const int* in_sizes, int n_in,
                              void* d_out, int out_size, void* d_ws, size_t ws_size,
                              hipStream_t stream) {
  const float* enc_f  = (const float*)d_in[0];
  const int*   target = (const int*)d_in[1];
  const float* emb    = (const float*)d_in[2];
  const float* Wq     = (const float*)d_in[3];
  const float* bq     = (const float*)d_in[4];
  const float* Wk     = (const float*)d_in[5];
  const float* bk     = (const float*)d_in[6];
  const float* Wa     = (const float*)d_in[7];
  // d_in[8] = ba : cancels in softmax (shift invariance) -> unused
  const float* W_ih   = (const float*)d_in[9];
  const float* b_ih   = (const float*)d_in[10];
  const float* W_hh   = (const float*)d_in[11];
  const float* b_hh   = (const float*)d_in[12];
  const float* W_lin  = (const float*)d_in[13];
  const float* b_lin  = (const float*)d_in[14];
  float* out = (float*)d_out;

  char* ws = (char*)d_ws;
  size_t off = 0;
  auto alloc = [&](size_t bytes) -> void* {
    void* p = ws + off;
    off += (bytes + 255) & ~(size_t)255;
    return p;
  };
  unsigned short* Wlin_b = (unsigned short*)alloc((size_t)V_ * H_ * 2);
  unsigned short* Wq_b   = (unsigned short*)alloc((size_t)H_ * H_ * 2);
  unsigned short* Wk_b   = (unsigned short*)alloc((size_t)H_ * H_ * 2);
  unsigned short* Wih_b  = (unsigned short*)alloc((size_t)3 * H_ * (H_ + E_) * 2);
  unsigned short* Whh_b  = (unsigned short*)alloc((size_t)3 * H_ * H_ * 2);
  unsigned short* enc_b  = (unsigned short*)alloc((size_t)B_ * S_ * H_ * 2);
  unsigned short* keys_b = (unsigned short*)alloc((size_t)B_ * S_ * H_ * 2);
  unsigned short* tok_b  = (unsigned short*)alloc((size_t)(T_ - 1) * B_ * E_ * 2);
  float*          state  = (float*)alloc((size_t)B_ * H_ * 4);
  unsigned short* state_b= (unsigned short*)alloc((size_t)B_ * H_ * 2);
  float*          qbuf   = (float*)alloc((size_t)B_ * H_ * 4);
  unsigned short* xbuf   = (unsigned short*)alloc((size_t)B_ * (E_ + H_) * 2);
  float*          gibuf  = (float*)alloc((size_t)B_ * 3 * H_ * 4);
  float*          ghbuf  = (float*)alloc((size_t)B_ * 3 * H_ * 4);

  auto cvt = [&](const float* in, unsigned short* o, size_t n) {
    cvt_kernel<<<dim3((unsigned)((n / 4 + 255) / 256)), 256, 0, stream>>>(in, o, (int)(n / 4));
  };
  cvt(W_lin, Wlin_b, (size_t)V_ * H_);
  cvt(Wq,    Wq_b,   (size_t)H_ * H_);
  cvt(Wk,    Wk_b,   (size_t)H_ * H_);
  cvt(W_ih,  Wih_b,  (size_t)3 * H_ * (H_ + E_));
  cvt(W_hh,  Whh_b,  (size_t)3 * H_ * H_);
  cvt(enc_f, enc_b,  (size_t)B_ * S_ * H_);

  tok_gather_kernel<<<dim3((T_ - 1) * B_ * E_ / 256), 256, 0, stream>>>(emb, target, tok_b);
  init_state_kernel<<<dim3(B_ * H_ / 256), 256, 0, stream>>>(enc_f, state, state_b);
  sos_kernel<<<dim3(B_ * V_ / 256), 256, 0, stream>>>(out);

  // keys = enc @ Wk^T + bk   (M = B*S, N = H, K = H) -> bf16
  gemm_bt_kernel<true><<<dim3(H_ / 64, B_ * S_ / 64), 256, 0, stream>>>(
      enc_b, H_, Wk_b, H_, bk, keys_b, H_, H_);

  for (int t = 0; t < T_ - 1; ++t) {
    // q = state @ Wq^T + bq  AND  gh = state @ W_hh^T + b_hh  (merged, same A)
    qgh_gemm_kernel<<<dim3(H_ / 64 + 3 * H_ / 64), 256, 0, stream>>>(
        state_b, Wq_b, bq, qbuf, Whh_b, b_hh, ghbuf);
    // attention + build x = [token, context]
    attn_kernel<<<dim3(B_), 512, 0, stream>>>(
        qbuf, keys_b, enc_b, Wa, tok_b + (size_t)t * B_ * E_, xbuf);
    // gi = x @ W_ih^T + b_ih
    gemm_bt_kernel<false><<<dim3(3 * H_ / 64, 1), 256, 0, stream>>>(
        xbuf, E_ + H_, Wih_b, E_ + H_, b_ih, gibuf, 3 * H_, E_ + H_);
    // GRU gates -> new state
    gate_kernel<<<dim3(B_ * H_ / 256), 256, 0, stream>>>(gibuf, ghbuf, state, state_b);
    // pred = new_state @ W_lin^T + b_lin -> out[:, t+1, :]
    gemm_bt_kernel<false><<<dim3(V_ / 64, 1), 256, 0, stream>>>(
        state_b, H_, Wlin_b, H_, b_lin, out + (size_t)(t + 1) * V_, (long long)T_ * V_, H_);
  }
}

// Round 8
// 3131.102 us; speedup vs baseline: 1.4047x; 1.4047x over previous
//
#include <hip/hip_runtime.h>
#include <hip/hip_bf16.h>
#include <cstdint>
#include <cstddef>

typedef __attribute__((ext_vector_type(8))) short short8;
typedef __attribute__((ext_vector_type(4))) float f32x4;
typedef __attribute__((ext_vector_type(4))) unsigned short ushort4v;

#define B_ 64
#define S_ 128
#define T_ 32
#define H_ 1024
#define E_ 512
#define V_ 32000

__device__ __forceinline__ float bf2f(unsigned short s) {
  union { unsigned u; float f; } cv;
  cv.u = ((unsigned)s) << 16;
  return cv.f;
}
__device__ __forceinline__ unsigned short f2bf_bits(float f) {
  __hip_bfloat16 h = __float2bfloat16(f);
  return __builtin_bit_cast(unsigned short, h);
}

// ---------------- conversion / setup kernels ----------------

__global__ __launch_bounds__(256) void cvt_kernel(const float* __restrict__ in,
                                                  unsigned short* __restrict__ out, int n4) {
  int i = blockIdx.x * 256 + threadIdx.x;
  if (i >= n4) return;
  float4 v = ((const float4*)in)[i];
  ushort4v o;
  o.x = f2bf_bits(v.x); o.y = f2bf_bits(v.y); o.z = f2bf_bits(v.z); o.w = f2bf_bits(v.w);
  ((ushort4v*)out)[i] = o;
}

__global__ __launch_bounds__(256) void tok_gather_kernel(const float* __restrict__ emb,
                                                         const int* __restrict__ target,
                                                         unsigned short* __restrict__ tok) {
  int i = blockIdx.x * 256 + threadIdx.x;   // over (T-1)*B*E
  int e = i & (E_ - 1);
  int rest = i >> 9;        // / E_
  int b = rest & (B_ - 1);
  int t = rest >> 6;        // / B_
  int tg = target[b * T_ + t];
  tok[i] = f2bf_bits(emb[(size_t)tg * E_ + e]);
}

__global__ __launch_bounds__(256) void init_state_kernel(const float* __restrict__ enc,
                                                         float* __restrict__ state,
                                                         unsigned short* __restrict__ state_bf) {
  int i = blockIdx.x * 256 + threadIdx.x;   // B*H
  int b = i >> 10;
  int h = i & (H_ - 1);
  float v = enc[((size_t)b * S_ + (S_ - 1)) * H_ + h];
  state[i] = v;
  state_bf[i] = f2bf_bits(v);
}

__global__ __launch_bounds__(256) void sos_kernel(float* __restrict__ out) {
  int i = blockIdx.x * 256 + threadIdx.x;   // B*V
  int b = i / V_;
  int v = i - b * V_;
  out[(size_t)b * T_ * V_ + v] = (v == 1) ? 1.0f : 0.0f;
}

// ---------------- bf16 MFMA GEMM:  C[M,N] = A[M,K] * B[N,K]^T + bias ----------------
// Works for 1-wave (64-thr) or 4-wave (256-thr) blocks; wave w covers 16 cols.
// A/B fragments: m/n = lane&15, k-slot = (lane>>4)*8 + j (same map for A and B, so
// any HW k-permutation cancels). C/D: col = lane&15, row = (lane>>4)*4 + reg
// [measured: learn_hip m89/m91].

template<bool OUT_BF16>
__device__ __forceinline__ void gemm_bt_device(
    const unsigned short* __restrict__ A, int lda,
    const unsigned short* __restrict__ Bm, int ldb,
    const float* __restrict__ bias,
    void* __restrict__ C, long long ldc,
    int K, int bn, int bm)
{
  const int wave = threadIdx.x >> 6;
  const int lane = threadIdx.x & 63;
  const int n0 = bn + wave * 16 + (lane & 15);
  const int ar = lane & 15;
  const int kg = (lane >> 4) * 8;

  const unsigned short* Bp = Bm + (size_t)n0 * ldb + kg;
  const unsigned short* Ap = A + (size_t)(bm + ar) * lda + kg;

  f32x4 acc0 = {0.f,0.f,0.f,0.f};
  f32x4 acc1 = {0.f,0.f,0.f,0.f};
  f32x4 acc2 = {0.f,0.f,0.f,0.f};
  f32x4 acc3 = {0.f,0.f,0.f,0.f};

  #pragma unroll 2
  for (int kk = 0; kk < K; kk += 32) {
    short8 bfrag = *(const short8*)(Bp + kk);
    short8 a0 = *(const short8*)(Ap + kk);
    short8 a1 = *(const short8*)(Ap + (size_t)16 * lda + kk);
    short8 a2 = *(const short8*)(Ap + (size_t)32 * lda + kk);
    short8 a3 = *(const short8*)(Ap + (size_t)48 * lda + kk);
    acc0 = __builtin_amdgcn_mfma_f32_16x16x32_bf16(a0, bfrag, acc0, 0, 0, 0);
    acc1 = __builtin_amdgcn_mfma_f32_16x16x32_bf16(a1, bfrag, acc1, 0, 0, 0);
    acc2 = __builtin_amdgcn_mfma_f32_16x16x32_bf16(a2, bfrag, acc2, 0, 0, 0);
    acc3 = __builtin_amdgcn_mfma_f32_16x16x32_bf16(a3, bfrag, acc3, 0, 0, 0);
  }

  const float bv = bias[n0];
  const int rbase = bm + (lane >> 4) * 4;
  f32x4 accs[4] = {acc0, acc1, acc2, acc3};
  #pragma unroll
  for (int mt = 0; mt < 4; ++mt) {
    #pragma unroll
    for (int r = 0; r < 4; ++r) {
      float v = accs[mt][r] + bv;
      size_t idx = (size_t)(rbase + mt * 16 + r) * (size_t)ldc + n0;
      if (OUT_BF16) ((unsigned short*)C)[idx] = f2bf_bits(v);
      else          ((float*)C)[idx] = v;
    }
  }
}

template<bool OUT_BF16>
__global__ __launch_bounds__(256) void gemm_bt_kernel(
    const unsigned short* __restrict__ A, int lda,
    const unsigned short* __restrict__ Bm, int ldb,
    const float* __restrict__ bias,
    void* __restrict__ C, long long ldc,
    int K)
{
  gemm_bt_device<OUT_BF16>(A, lda, Bm, ldb, bias, C, ldc, K,
                           blockIdx.x * 64, blockIdx.y * 64);
}

// Merged q + gh GEMM, 1-wave blocks for max CU spread (256 blocks x 64 thr).
// blocks [0, 64):   q  = state @ Wq^T  + bq  -> qbuf  (16 cols each)
// blocks [64, 256): gh = state @ W_hh^T+ bhh -> ghbuf (16 cols each)
__global__ __launch_bounds__(64) void qgh_gemm_kernel(
    const unsigned short* __restrict__ state_b,
    const unsigned short* __restrict__ Wq_b, const float* __restrict__ bq,
    float* __restrict__ qbuf,
    const unsigned short* __restrict__ Whh_b, const float* __restrict__ bhh,
    float* __restrict__ ghbuf)
{
  if (blockIdx.x < H_ / 16) {
    gemm_bt_device<false>(state_b, H_, Wq_b, H_, bq, qbuf, H_, H_,
                          blockIdx.x * 16, 0);
  } else {
    gemm_bt_device<false>(state_b, H_, Whh_b, H_, bhh, ghbuf, 3 * H_, H_,
                          (blockIdx.x - H_ / 16) * 16, 0);
  }
}

// ---------------- fused GRU kernel: gi_ctx GEMM (3 gate tiles) + gate math ----------
// 64 blocks x 64 threads (1 wave); block x owns h-columns [x*16, x*16+16).
// acc{R,Z,N}[row, col] = sum_k ctx[row,k] * W_ih[g*H+col, E+k]  (K=1024), then adds
// precomputed git (token part incl. b_ih), loads gh/state, applies GRU gate,
// writes state, state_bf, st_all slot. All acc indices compile-time (rule #20).

__global__ __launch_bounds__(64) void gru_kernel(
    const unsigned short* __restrict__ ctx,    // [B_, H_] bf16
    const unsigned short* __restrict__ Wih_b,  // [3H, H+E] bf16
    const float* __restrict__ git,             // [B_, 3H] token-part gi (+b_ih), this t
    const float* __restrict__ gh,              // [B_, 3H]
    float* __restrict__ state,                 // [B_, H_] fp32
    unsigned short* __restrict__ state_bf,     // [B_, H_] bf16
    unsigned short* __restrict__ st_slot)      // st_all + t*B*H
{
  const int lane = threadIdx.x & 63;
  const int colc = blockIdx.x * 16 + (lane & 15);      // h-column in [0,H)
  const int ar = lane & 15;
  const int kg = (lane >> 4) * 8;

  const unsigned short* Ap  = ctx + (size_t)ar * H_ + kg;
  const unsigned short* BpR = Wih_b + (size_t)colc            * (H_ + E_) + E_ + kg;
  const unsigned short* BpZ = Wih_b + (size_t)(H_ + colc)     * (H_ + E_) + E_ + kg;
  const unsigned short* BpN = Wih_b + (size_t)(2 * H_ + colc) * (H_ + E_) + E_ + kg;

  f32x4 aR0 = {0,0,0,0}, aR1 = {0,0,0,0}, aR2 = {0,0,0,0}, aR3 = {0,0,0,0};
  f32x4 aZ0 = {0,0,0,0}, aZ1 = {0,0,0,0}, aZ2 = {0,0,0,0}, aZ3 = {0,0,0,0};
  f32x4 aN0 = {0,0,0,0}, aN1 = {0,0,0,0}, aN2 = {0,0,0,0}, aN3 = {0,0,0,0};

  for (int kk = 0; kk < H_; kk += 32) {
    short8 a0 = *(const short8*)(Ap + kk);
    short8 a1 = *(const short8*)(Ap + (size_t)16 * H_ + kk);
    short8 a2 = *(const short8*)(Ap + (size_t)32 * H_ + kk);
    short8 a3 = *(const short8*)(Ap + (size_t)48 * H_ + kk);
    short8 bR = *(const short8*)(BpR + kk);
    short8 bZ = *(const short8*)(BpZ + kk);
    short8 bN = *(const short8*)(BpN + kk);
    aR0 = __builtin_amdgcn_mfma_f32_16x16x32_bf16(a0, bR, aR0, 0, 0, 0);
    aR1 = __builtin_amdgcn_mfma_f32_16x16x32_bf16(a1, bR, aR1, 0, 0, 0);
    aR2 = __builtin_amdgcn_mfma_f32_16x16x32_bf16(a2, bR, aR2, 0, 0, 0);
    aR3 = __builtin_amdgcn_mfma_f32_16x16x32_bf16(a3, bR, aR3, 0, 0, 0);
    aZ0 = __builtin_amdgcn_mfma_f32_16x16x32_bf16(a0, bZ, aZ0, 0, 0, 0);
    aZ1 = __builtin_amdgcn_mfma_f32_16x16x32_bf16(a1, bZ, aZ1, 0, 0, 0);
    aZ2 = __builtin_amdgcn_mfma_f32_16x16x32_bf16(a2, bZ, aZ2, 0, 0, 0);
    aZ3 = __builtin_amdgcn_mfma_f32_16x16x32_bf16(a3, bZ, aZ3, 0, 0, 0);
    aN0 = __builtin_amdgcn_mfma_f32_16x16x32_bf16(a0, bN, aN0, 0, 0, 0);
    aN1 = __builtin_amdgcn_mfma_f32_16x16x32_bf16(a1, bN, aN1, 0, 0, 0);
    aN2 = __builtin_amdgcn_mfma_f32_16x16x32_bf16(a2, bN, aN2, 0, 0, 0);
    aN3 = __builtin_amdgcn_mfma_f32_16x16x32_bf16(a3, bN, aN3, 0, 0, 0);
  }

  f32x4 accR[4] = {aR0, aR1, aR2, aR3};
  f32x4 accZ[4] = {aZ0, aZ1, aZ2, aZ3};
  f32x4 accN[4] = {aN0, aN1, aN2, aN3};
  const int rb = (lane >> 4) * 4;

  #pragma unroll
  for (int mt = 0; mt < 4; ++mt) {
    #pragma unroll
    for (int r = 0; r < 4; ++r) {
      const int row = mt * 16 + rb + r;               // b index
      const size_t g3 = (size_t)row * 3 * H_;
      float ir  = accR[mt][r] + git[g3 + colc];
      float iz  = accZ[mt][r] + git[g3 + H_ + colc];
      float inn = accN[mt][r] + git[g3 + 2 * H_ + colc];
      float hr  = gh[g3 + colc];
      float hz  = gh[g3 + H_ + colc];
      float hn  = gh[g3 + 2 * H_ + colc];
      const size_t si = (size_t)row * H_ + colc;
      float rr = 1.f / (1.f + __expf(-(ir + hr)));
      float zz = 1.f / (1.f + __expf(-(iz + hz)));
      float tt = inn + rr * hn;
      tt = fminf(fmaxf(tt, -15.f), 15.f);
      float e = __expf(2.f * tt);
      float nn = (e - 1.f) / (e + 1.f);
      float ns = (1.f - zz) * nn + zz * state[si];
      state[si] = ns;
      unsigned short nb = f2bf_bits(ns);
      state_bf[si] = nb;
      st_slot[si] = nb;
    }
  }
}

// ---------------- batched pred GEMM (after the loop) ----------------
// C[M=1984, N=32000] = st_all[M, K=1024] @ Wlin^T + b_lin, scattered to
// out[b, t+1, :] with m = t*64 + b.
// Tile 64(M) x 256(N): 4 waves, each wave 64x64 via 4x4 fragments.
// grid.x = m-tile (FAST) so the 31 m-tiles sharing one B column-panel are
// co-resident -> B panel stays L2-hot.

__global__ __launch_bounds__(256) void pred_gemm_kernel(
    const unsigned short* __restrict__ A,   // st_all [1984,1024]
    const unsigned short* __restrict__ Bm,  // Wlin_b [32000,1024]
    const float* __restrict__ bias,         // b_lin
    float* __restrict__ out)                // [B, T, V]
{
  const int bm = blockIdx.x * 64;
  const int bn = blockIdx.y * 256;
  const int wave = threadIdx.x >> 6;
  const int lane = threadIdx.x & 63;
  const int ar = lane & 15;
  const int kg = (lane >> 4) * 8;
  const int n0 = bn + wave * 64 + (lane & 15);

  const unsigned short* Ap = A + (size_t)(bm + ar) * H_ + kg;
  const unsigned short* Bp = Bm + (size_t)n0 * H_ + kg;

  f32x4 acc[4][4];   // [mt][nt]
  #pragma unroll
  for (int i = 0; i < 4; ++i)
    #pragma unroll
    for (int j = 0; j < 4; ++j) acc[i][j] = (f32x4){0.f,0.f,0.f,0.f};

  for (int kk = 0; kk < H_; kk += 32) {
    short8 a0 = *(const short8*)(Ap + kk);
    short8 a1 = *(const short8*)(Ap + (size_t)16 * H_ + kk);
    short8 a2 = *(const short8*)(Ap + (size_t)32 * H_ + kk);
    short8 a3 = *(const short8*)(Ap + (size_t)48 * H_ + kk);
    short8 b0 = *(const short8*)(Bp + kk);
    short8 b1 = *(const short8*)(Bp + (size_t)16 * H_ + kk);
    short8 b2 = *(const short8*)(Bp + (size_t)32 * H_ + kk);
    short8 b3 = *(const short8*)(Bp + (size_t)48 * H_ + kk);
    acc[0][0] = __builtin_amdgcn_mfma_f32_16x16x32_bf16(a0, b0, acc[0][0], 0, 0, 0);
    acc[0][1] = __builtin_amdgcn_mfma_f32_16x16x32_bf16(a0, b1, acc[0][1], 0, 0, 0);
    acc[0][2] = __builtin_amdgcn_mfma_f32_16x16x32_bf16(a0, b2, acc[0][2], 0, 0, 0);
    acc[0][3] = __builtin_amdgcn_mfma_f32_16x16x32_bf16(a0, b3, acc[0][3], 0, 0, 0);
    acc[1][0] = __builtin_amdgcn_mfma_f32_16x16x32_bf16(a1, b0, acc[1][0], 0, 0, 0);
    acc[1][1] = __builtin_amdgcn_mfma_f32_16x16x32_bf16(a1, b1, acc[1][1], 0, 0, 0);
    acc[1][2] = __builtin_amdgcn_mfma_f32_16x16x32_bf16(a1, b2, acc[1][2], 0, 0, 0);
    acc[1][3] = __builtin_amdgcn_mfma_f32_16x16x32_bf16(a1, b3, acc[1][3], 0, 0, 0);
    acc[2][0] = __builtin_amdgcn_mfma_f32_16x16x32_bf16(a2, b0, acc[2][0], 0, 0, 0);
    acc[2][1] = __builtin_amdgcn_mfma_f32_16x16x32_bf16(a2, b1, acc[2][1], 0, 0, 0);
    acc[2][2] = __builtin_amdgcn_mfma_f32_16x16x32_bf16(a2, b2, acc[2][2], 0, 0, 0);
    acc[2][3] = __builtin_amdgcn_mfma_f32_16x16x32_bf16(a2, b3, acc[2][3], 0, 0, 0);
    acc[3][0] = __builtin_amdgcn_mfma_f32_16x16x32_bf16(a3, b0, acc[3][0], 0, 0, 0);
    acc[3][1] = __builtin_amdgcn_mfma_f32_16x16x32_bf16(a3, b1, acc[3][1], 0, 0, 0);
    acc[3][2] = __builtin_amdgcn_mfma_f32_16x16x32_bf16(a3, b2, acc[3][2], 0, 0, 0);
    acc[3][3] = __builtin_amdgcn_mfma_f32_16x16x32_bf16(a3, b3, acc[3][3], 0, 0, 0);
  }

  const int rbase = (lane >> 4) * 4;
  #pragma unroll
  for (int mt = 0; mt < 4; ++mt) {
    const int m = bm + mt * 16 + rbase;   // + r below
    #pragma unroll
    for (int nt = 0; nt < 4; ++nt) {
      const int col = n0 + nt * 16;
      const float bv = bias[col];
      #pragma unroll
      for (int r = 0; r < 4; ++r) {
        int mm = m + r;
        int t = mm >> 6;
        int b = mm & (B_ - 1);
        out[(size_t)b * T_ * V_ + (size_t)(t + 1) * V_ + col] = acc[mt][nt][r] + bv;
      }
    }
  }
}

// ---------------- fused attention (one block per batch element) ----------------

__global__ __launch_bounds__(512) void attn_kernel(
    const float* __restrict__ q,
    const unsigned short* __restrict__ keys,
    const unsigned short* __restrict__ enc,
    const float* __restrict__ Wa,
    unsigned short* __restrict__ ctxout)      // [B_, H_] bf16
{
  const int b = blockIdx.x;
  const int tid = threadIdx.x;
  __shared__ float s_q[H_];
  __shared__ float s_wa[H_];
  __shared__ float s_part[512];
  __shared__ float s_w[S_];
  __shared__ float s_bcast;

  for (int i = tid; i < H_; i += 512) { s_q[i] = q[b * H_ + i]; s_wa[i] = Wa[i]; }
  __syncthreads();

  {
    const int s = tid & (S_ - 1);
    const int h0 = (tid >> 7) * 256;
    const short8* kp = (const short8*)(keys + ((size_t)b * S_ + s) * H_ + h0);
    float acc = 0.f;
    #pragma unroll 4
    for (int hv = 0; hv < 32; ++hv) {   // 32*8 = 256 elems
      short8 kv = kp[hv];
      #pragma unroll
      for (int j = 0; j < 8; ++j) {
        int h = h0 + hv * 8 + j;
        float v = s_q[h] + bf2f((unsigned short)kv[j]);
        v = fminf(fmaxf(v, -15.f), 15.f);
        float e = __expf(2.f * v);
        float th = (e - 1.f) / (e + 1.f);
        acc += s_wa[h] * th;
      }
    }
    s_part[tid] = acc;
  }
  __syncthreads();
  if (tid < S_) {
    s_w[tid] = s_part[tid] + s_part[tid + 128] + s_part[tid + 256] + s_part[tid + 384];
  }
  __syncthreads();
  if (tid < 64) {
    float m = fmaxf(s_w[tid], s_w[tid + 64]);
    #pragma unroll
    for (int off = 32; off > 0; off >>= 1) m = fmaxf(m, __shfl_xor(m, off));
    if (tid == 0) s_bcast = m;
  }
  __syncthreads();
  const float mx = s_bcast;
  if (tid < S_) s_w[tid] = __expf(s_w[tid] - mx);
  __syncthreads();
  if (tid < 64) {
    float sm = s_w[tid] + s_w[tid + 64];
    #pragma unroll
    for (int off = 32; off > 0; off >>= 1) sm += __shfl_xor(sm, off);
    if (tid == 0) s_bcast = sm;
  }
  __syncthreads();
  const float inv = 1.0f / s_bcast;

  {
    float c0 = 0.f, c1 = 0.f;
    const unsigned short* ep = enc + (size_t)b * S_ * H_;
    #pragma unroll 4
    for (int s = 0; s < S_; ++s) {
      float w = s_w[s];
      c0 += w * bf2f(ep[s * H_ + tid]);
      c1 += w * bf2f(ep[s * H_ + tid + 512]);
    }
    c0 *= inv; c1 *= inv;
    ctxout[b * H_ + tid]       = f2bf_bits(c0);
    ctxout[b * H_ + tid + 512] = f2bf_bits(c1);
  }
}

// ---------------- launcher ----------------

extern "C" void kernel_launch(void* const* d_in, const int* in_sizes, int n_in,
                              void* d_out, int out_size, void* d_ws, size_t ws_size,
                              hipStream_t stream) {
  const float* enc_f  = (const float*)d_in[0];
  const int*   target = (const int*)d_in[1];
  const float* emb    = (const float*)d_in[2];
  const float* Wq     = (const float*)d_in[3];
  const float* bq     = (const float*)d_in[4];
  const float* Wk     = (const float*)d_in[5];
  const float* bk     = (const float*)d_in[6];
  const float* Wa     = (const float*)d_in[7];
  // d_in[8] = ba : cancels in softmax (shift invariance) -> unused
  const float* W_ih   = (const float*)d_in[9];
  const float* b_ih   = (const float*)d_in[10];
  const float* W_hh   = (const float*)d_in[11];
  const float* b_hh   = (const float*)d_in[12];
  const float* W_lin  = (const float*)d_in[13];
  const float* b_lin  = (const float*)d_in[14];
  float* out = (float*)d_out;

  char* ws = (char*)d_ws;
  size_t off = 0;
  auto alloc = [&](size_t bytes) -> void* {
    void* p = ws + off;
    off += (bytes + 255) & ~(size_t)255;
    return p;
  };
  unsigned short* Wlin_b  = (unsigned short*)alloc((size_t)V_ * H_ * 2);
  unsigned short* Wq_b    = (unsigned short*)alloc((size_t)H_ * H_ * 2);
  unsigned short* Wk_b    = (unsigned short*)alloc((size_t)H_ * H_ * 2);
  unsigned short* Wih_b   = (unsigned short*)alloc((size_t)3 * H_ * (H_ + E_) * 2);
  unsigned short* Whh_b   = (unsigned short*)alloc((size_t)3 * H_ * H_ * 2);
  unsigned short* enc_b   = (unsigned short*)alloc((size_t)B_ * S_ * H_ * 2);
  unsigned short* keys_b  = (unsigned short*)alloc((size_t)B_ * S_ * H_ * 2);
  unsigned short* tok_b   = (unsigned short*)alloc((size_t)(T_ - 1) * B_ * E_ * 2);
  float*          state   = (float*)alloc((size_t)B_ * H_ * 4);
  unsigned short* state_b = (unsigned short*)alloc((size_t)B_ * H_ * 2);
  unsigned short* st_all  = (unsigned short*)alloc((size_t)(T_ - 1) * B_ * H_ * 2);
  float*          qbuf    = (float*)alloc((size_t)B_ * H_ * 4);
  unsigned short* ctxbuf  = (unsigned short*)alloc((size_t)B_ * H_ * 2);
  float*          ghbuf   = (float*)alloc((size_t)B_ * 3 * H_ * 4);
  float*          git_all = (float*)alloc((size_t)(T_ - 1) * B_ * 3 * H_ * 4);

  auto cvt = [&](const float* in, unsigned short* o, size_t n) {
    cvt_kernel<<<dim3((unsigned)((n / 4 + 255) / 256)), 256, 0, stream>>>(in, o, (int)(n / 4));
  };
  cvt(W_lin, Wlin_b, (size_t)V_ * H_);
  cvt(Wq,    Wq_b,   (size_t)H_ * H_);
  cvt(Wk,    Wk_b,   (size_t)H_ * H_);
  cvt(W_ih,  Wih_b,  (size_t)3 * H_ * (H_ + E_));
  cvt(W_hh,  Whh_b,  (size_t)3 * H_ * H_);
  cvt(enc_f, enc_b,  (size_t)B_ * S_ * H_);

  tok_gather_kernel<<<dim3((T_ - 1) * B_ * E_ / 256), 256, 0, stream>>>(emb, target, tok_b);
  init_state_kernel<<<dim3(B_ * H_ / 256), 256, 0, stream>>>(enc_f, state, state_b);
  sos_kernel<<<dim3(B_ * V_ / 256), 256, 0, stream>>>(out);

  // keys = enc @ Wk^T + bk   (M = B*S, N = H, K = H) -> bf16
  gemm_bt_kernel<true><<<dim3(H_ / 64, B_ * S_ / 64), 256, 0, stream>>>(
      enc_b, H_, Wk_b, H_, bk, keys_b, H_, H_);

  // git_all = tok @ W_ih[:, :E]^T + b_ih  (M = (T-1)*B = 1984, N = 3H, K = E)
  gemm_bt_kernel<false><<<dim3(3 * H_ / 64, (T_ - 1) * B_ / 64), 256, 0, stream>>>(
      tok_b, E_, Wih_b, H_ + E_, b_ih, git_all, 3 * H_, E_);

  for (int t = 0; t < T_ - 1; ++t) {
    // q = state @ Wq^T + bq  AND  gh = state @ W_hh^T + b_hh  (merged, same A;
    // 1-wave blocks: 256 blocks over 256 CUs)
    qgh_gemm_kernel<<<dim3(H_ / 16 + 3 * H_ / 16), 64, 0, stream>>>(
        state_b, Wq_b, bq, qbuf, Whh_b, b_hh, ghbuf);
    // attention -> context
    attn_kernel<<<dim3(B_), 512, 0, stream>>>(
        qbuf, keys_b, enc_b, Wa, ctxbuf);
    // gi_ctx GEMM + GRU gate fuse -> state, st_all[t] (1-wave blocks, 64 CUs)
    gru_kernel<<<dim3(H_ / 16), 64, 0, stream>>>(
        ctxbuf, Wih_b, git_all + (size_t)t * B_ * 3 * H_, ghbuf,
        state, state_b, st_all + (size_t)t * B_ * H_);
  }

  // All 31 pred GEMMs batched: [1984,1024] @ Wlin^T -> scatter to out[:,1:,:]
  pred_gemm_kernel<<<dim3((T_ - 1), V_ / 256), 256, 0, stream>>>(
      st_all, Wlin_b, b_lin, out);
}